// Round 1
// baseline (260.701 us; speedup 1.0000x reference)
//
#include <hip/hip_runtime.h>
#include <hip/hip_bf16.h>
#include <stdint.h>

typedef unsigned short u16;
typedef __attribute__((ext_vector_type(8))) short bf16x8;
typedef __attribute__((ext_vector_type(4))) float f32x4;

#define B_    8
#define L_    273
#define DIM_  1536
#define NH_   12
#define DH_   128
#define ZS_   256
#define FH_   32
#define MROWS (B_ * L_)   /* 2184 */
#define MPAD  2304        /* 18 * 128 */
#define NQKV  4608

/* workspace offsets (bytes), all 16B-aligned */
#define OFF_XB    0ULL                      /* 2304*1536*2 = 7,077,888  */
#define OFF_WB    7077888ULL                /* 4608*1536*2 = 14,155,776 */
#define OFF_WOB   21233664ULL               /* 1536*1536*2 = 4,718,592  */
#define OFF_BQKV  25952256ULL               /* 4608*4      = 18,432     */
#define OFF_CQKV  25970688ULL               /* 2304*4608*4 = 42,467,328 */
#define OFF_ATTN  68438016ULL               /* 2304*1536*2 = 7,077,888  */
/* total ~75.5 MB */

__device__ __forceinline__ u16 f2bf(float f) {
  __hip_bfloat16 h = __float2bfloat16(f);
  return *reinterpret_cast<u16*>(&h);
}

__device__ __forceinline__ void gload_lds16(const u16* g, u16* l) {
  __builtin_amdgcn_global_load_lds(
      (const __attribute__((address_space(1))) void*)g,
      (__attribute__((address_space(3))) void*)l,
      16, 0, 0);
}

/* ---- elementwise f32 -> bf16 cast with zero-padding ---- */
__global__ void cast_pad_kernel(const float* __restrict__ src, u16* __restrict__ dst,
                                int n_src, int n_tot) {
  int i = blockIdx.x * 256 + threadIdx.x;
  if (i >= n_tot) return;
  float v = (i < n_src) ? src[i] : 0.f;
  dst[i] = f2bf(v);
}

__global__ void pack_bias_kernel(const float* __restrict__ bq, const float* __restrict__ bk,
                                 const float* __restrict__ bv, float* __restrict__ dst) {
  int i = blockIdx.x * 256 + threadIdx.x;
  if (i >= NQKV) return;
  float v;
  if (i < DIM_)            v = bq[i];
  else if (i < 2 * DIM_)   v = bk[i - DIM_];
  else                     v = bv[i - 2 * DIM_];
  dst[i] = v;
}

/* ---- bf16 GEMM, C[m,n] = sum_k A[m,k]*B[n,k] + bias[n]  (NT layout) ----
 * m97-style: 128x128 tile, BK=32, 4 waves (2x2), global_load_lds w=16,
 * mfma_f32_16x16x32_bf16, fp32 epilogue. grid = (N/128, Mpad/128), 256 thr. */
__global__ __launch_bounds__(256)
void gemm_bt_kernel(const u16* __restrict__ A, const u16* __restrict__ Bm,
                    const float* __restrict__ bias, float* __restrict__ C,
                    int K, int ldc, int Mvalid) {
  const int tn = blockIdx.x, tm = blockIdx.y;
  const int tid = threadIdx.x;
  const int lane = tid & 63;
  const int wid = tid >> 6;
  const int wm = wid >> 1, wn = wid & 1;

  __shared__ __align__(16) u16 As[128 * 32];
  __shared__ __align__(16) u16 Bs[128 * 32];

  f32x4 acc[4][4] = {};

  /* staging map: 4 threads per 64B row-chunk, 64 rows per issue */
  const int srow = tid >> 2;
  const int scol = (tid & 3) * 8;
  const u16* Abase = A + (size_t)(tm * 128 + srow) * K + scol;
  const u16* Bbase = Bm + (size_t)(tn * 128 + srow) * K + scol;
  u16* lAs = &As[srow * 32 + scol];
  u16* lBs = &Bs[srow * 32 + scol];
  const size_t rstep = (size_t)64 * K;

  const int ko = (lane >> 4) * 8;
  const int rA = wm * 64 + (lane & 15);
  const int rB = wn * 64 + (lane & 15);

  for (int kt = 0; kt < K; kt += 32) {
    __syncthreads();
    gload_lds16(Abase + kt,         lAs);
    gload_lds16(Abase + kt + rstep, lAs + 64 * 32);
    gload_lds16(Bbase + kt,         lBs);
    gload_lds16(Bbase + kt + rstep, lBs + 64 * 32);
    __syncthreads();

    bf16x8 af[4], bfr[4];
#pragma unroll
    for (int f = 0; f < 4; ++f) {
      af[f]  = *(const bf16x8*)&As[(rA + f * 16) * 32 + ko];
      bfr[f] = *(const bf16x8*)&Bs[(rB + f * 16) * 32 + ko];
    }
#pragma unroll
    for (int fm = 0; fm < 4; ++fm)
#pragma unroll
      for (int fn = 0; fn < 4; ++fn)
        acc[fm][fn] = __builtin_amdgcn_mfma_f32_16x16x32_bf16(af[fm], bfr[fn], acc[fm][fn], 0, 0, 0);
  }

  const int m0 = tm * 128 + wm * 64 + (lane >> 4) * 4;
  const int n0 = tn * 128 + wn * 64 + (lane & 15);
#pragma unroll
  for (int fm = 0; fm < 4; ++fm) {
#pragma unroll
    for (int fn = 0; fn < 4; ++fn) {
      const int n = n0 + fn * 16;
      const float bv = bias[n];
#pragma unroll
      for (int r = 0; r < 4; ++r) {
        const int m = m0 + fm * 16 + r;
        if (m < Mvalid) C[(size_t)m * ldc + n] = acc[fm][fn][r] + bv;
      }
    }
  }
}

/* ---- in-place RMSNorm on q,k sections of C_qkv; RoPE(q) with frame cf ---- */
__global__ __launch_bounds__(256)
void rmsnorm_rope_kernel(float* __restrict__ C, const float* __restrict__ g_q,
                         const float* __restrict__ g_k, const float* __restrict__ rope_table,
                         const int* __restrict__ cf_ptr) {
  const int m = blockIdx.x;            /* 0..MROWS-1 */
  const int l = m % L_;
  const int tid = threadIdx.x;
  const int cf = *cf_ptr;
  float* row = C + (size_t)m * NQKV;
  __shared__ float red[4];

  for (int sec = 0; sec < 2; ++sec) {
    float* p = row + sec * DIM_;
    const float* gw = sec ? g_k : g_q;
    float2 v[3];
    float ss = 0.f;
#pragma unroll
    for (int j = 0; j < 3; ++j) {
      int pj = tid + j * 256;          /* pair index 0..767 */
      v[j] = *(const float2*)&p[pj * 2];
      ss += v[j].x * v[j].x + v[j].y * v[j].y;
    }
#pragma unroll
    for (int o = 32; o; o >>= 1) ss += __shfl_xor(ss, o);
    if ((tid & 63) == 0) red[tid >> 6] = ss;
    __syncthreads();
    const float tot = red[0] + red[1] + red[2] + red[3];
    const float r = rsqrtf(tot * (1.f / DIM_) + 1e-6f);
#pragma unroll
    for (int j = 0; j < 3; ++j) {
      int pj = tid + j * 256;
      float y0 = v[j].x * r * gw[pj * 2];
      float y1 = v[j].y * r * gw[pj * 2 + 1];
      if (sec == 0) {                  /* rope on q only */
        float fr = rope_table[((size_t)cf * L_ + l) * 64 + (pj & 63)];
        float sn, cn;
        __sincosf(fr, &sn, &cn);
        float o0 = y0 * cn - y1 * sn;
        float o1 = y0 * sn + y1 * cn;
        y0 = o0; y1 = o1;
      }
      *(float2*)&p[pj * 2] = make_float2(y0, y1);
    }
    __syncthreads();
  }
}

/* ---- attention: one wave per (b,z,n); online softmax over g frames ---- */
__global__ __launch_bounds__(256)
void attention_kernel(const float* __restrict__ C, const float* __restrict__ cache_k,
                      const float* __restrict__ cache_v, const float* __restrict__ rope_table,
                      const int* __restrict__ rope_idx, const int* __restrict__ cf_ptr,
                      u16* __restrict__ attn_in) {
  const int w = blockIdx.x * 4 + (threadIdx.x >> 6);
  const int lane = threadIdx.x & 63;
  const int n = w % NH_;
  const int z = (w / NH_) & (ZS_ - 1);
  const int b = w / (NH_ * ZS_);
  const int cf = *cf_ptr;
  const int slot = cf % FH_;
  const int valid = min(cf + 1, FH_);
  const int d0 = lane * 2;

  const size_t crow = (size_t)(b * L_ + z) * NQKV + n * DH_ + d0;
  const float2 q = *(const float2*)&C[crow];

  float mx = -1e30f, lsum = 0.f, a0 = 0.f, a1 = 0.f;
  for (int g = 0; g < valid; ++g) {
    const int fi = rope_idx[g];
    const float fr = rope_table[((size_t)fi * L_ + z) * 64 + lane];
    float sn, cn;
    __sincosf(fr, &sn, &cn);
    const size_t coff = ((((size_t)b * FH_ + g) * L_ + z) * NH_ + n) * DH_ + d0;
    const float2 kv = (g == slot) ? *(const float2*)&C[crow + DIM_]
                                  : *(const float2*)&cache_k[coff];
    const float kr0 = kv.x * cn - kv.y * sn;
    const float kr1 = kv.x * sn + kv.y * cn;
    float part = q.x * kr0 + q.y * kr1;
#pragma unroll
    for (int o = 32; o; o >>= 1) part += __shfl_xor(part, o);
    const float score = part * 0.088388347648318447f; /* 1/sqrt(128) */
    const float nm = fmaxf(mx, score);
    const float scl = __expf(mx - nm);
    const float pw = __expf(score - nm);
    const float2 vv = (g == slot) ? *(const float2*)&C[crow + 2 * DIM_]
                                  : *(const float2*)&cache_v[coff];
    lsum = lsum * scl + pw;
    a0 = a0 * scl + pw * vv.x;
    a1 = a1 * scl + pw * vv.y;
    mx = nm;
  }
  const float inv = 1.f / lsum;
  const uint32_t packed = (uint32_t)f2bf(a0 * inv) | ((uint32_t)f2bf(a1 * inv) << 16);
  *(uint32_t*)&attn_in[(size_t)(b * L_ + z) * DIM_ + n * DH_ + d0] = packed;
}

/* ---- copy raw v rows (z >= ZS) into attn_in as bf16 ---- */
__global__ void vcond_kernel(const float* __restrict__ C, u16* __restrict__ attn_in) {
  int i = blockIdx.x * 256 + threadIdx.x;
  const int total = B_ * (L_ - ZS_) * DIM_;
  if (i >= total) return;
  int col = i % DIM_;
  int r = i / DIM_;
  int b = r / (L_ - ZS_);
  int lz = r % (L_ - ZS_);
  int mrow = b * L_ + ZS_ + lz;
  attn_in[(size_t)mrow * DIM_ + col] = f2bf(C[(size_t)mrow * NQKV + 2 * DIM_ + col]);
}

extern "C" void kernel_launch(void* const* d_in, const int* in_sizes, int n_in,
                              void* d_out, int out_size, void* d_ws, size_t ws_size,
                              hipStream_t stream) {
  const float* x       = (const float*)d_in[0];
  const float* w_q     = (const float*)d_in[1];
  const float* b_q     = (const float*)d_in[2];
  const float* w_k     = (const float*)d_in[3];
  const float* b_k     = (const float*)d_in[4];
  const float* w_v     = (const float*)d_in[5];
  const float* b_v     = (const float*)d_in[6];
  const float* w_o     = (const float*)d_in[7];
  const float* b_o     = (const float*)d_in[8];
  const float* g_q     = (const float*)d_in[9];
  const float* g_k     = (const float*)d_in[10];
  const float* cache_k = (const float*)d_in[11];
  const float* cache_v = (const float*)d_in[12];
  const float* rope_tb = (const float*)d_in[13];
  const int*   rope_ix = (const int*)d_in[14];
  const int*   cf      = (const int*)d_in[15];

  char* ws = (char*)d_ws;
  u16*   xb      = (u16*)(ws + OFF_XB);
  u16*   wb      = (u16*)(ws + OFF_WB);
  u16*   wob     = (u16*)(ws + OFF_WOB);
  float* bqkv    = (float*)(ws + OFF_BQKV);
  float* Cq      = (float*)(ws + OFF_CQKV);
  u16*   attn_in = (u16*)(ws + OFF_ATTN);

  const int WN = DIM_ * DIM_; /* 2,359,296 */

  cast_pad_kernel<<<(MPAD * DIM_ + 255) / 256, 256, 0, stream>>>(x, xb, MROWS * DIM_, MPAD * DIM_);
  cast_pad_kernel<<<(WN + 255) / 256, 256, 0, stream>>>(w_q, wb,           WN, WN);
  cast_pad_kernel<<<(WN + 255) / 256, 256, 0, stream>>>(w_k, wb + WN,      WN, WN);
  cast_pad_kernel<<<(WN + 255) / 256, 256, 0, stream>>>(w_v, wb + 2 * WN,  WN, WN);
  cast_pad_kernel<<<(WN + 255) / 256, 256, 0, stream>>>(w_o, wob,          WN, WN);
  pack_bias_kernel<<<(NQKV + 255) / 256, 256, 0, stream>>>(b_q, b_k, b_v, bqkv);

  /* QKV projection: (2304 x 4608 x 1536) */
  gemm_bt_kernel<<<dim3(NQKV / 128, MPAD / 128), 256, 0, stream>>>(xb, wb, bqkv, Cq, DIM_, NQKV, MPAD);

  /* RMSNorm(q,k) + RoPE(q), in place */
  rmsnorm_rope_kernel<<<MROWS, 256, 0, stream>>>(Cq, g_q, g_k, rope_tb, cf);

  /* temporal attention over frames (z < ZS) */
  attention_kernel<<<(B_ * ZS_ * NH_) / 4, 256, 0, stream>>>(Cq, cache_k, cache_v, rope_tb, rope_ix, cf, attn_in);

  /* passthrough v for z >= ZS */
  vcond_kernel<<<(B_ * (L_ - ZS_) * DIM_ + 255) / 256, 256, 0, stream>>>(Cq, attn_in);

  /* output projection: (2304 x 1536 x 1536), guarded at 2184 rows */
  gemm_bt_kernel<<<dim3(DIM_ / 128, MPAD / 128), 256, 0, stream>>>(attn_in, wob, b_o, (float*)d_out, DIM_, DIM_, MROWS);
}

// Round 2
// 250.108 us; speedup vs baseline: 1.0424x; 1.0424x over previous
//
#include <hip/hip_runtime.h>
#include <hip/hip_bf16.h>
#include <stdint.h>

typedef unsigned short u16;
typedef __attribute__((ext_vector_type(8))) short bf16x8;
typedef __attribute__((ext_vector_type(4))) float f32x4;

#define B_    8
#define L_    273
#define DIM_  1536
#define NH_   12
#define DH_   128
#define ZS_   256
#define FH_   32
#define MROWS (B_ * L_)   /* 2184 */
#define MPAD  2304        /* 18 * 128 */
#define NQKV  4608

/* workspace offsets (bytes), all 16B-aligned */
#define OFF_XB    0ULL                      /* 2304*1536*2  = 7,077,888  */
#define OFF_WB    7077888ULL                /* 4608*1536*2  = 14,155,776 */
#define OFF_WOB   21233664ULL               /* 1536*1536*2  = 4,718,592  */
#define OFF_BQKV  25952256ULL               /* 4608*4       = 18,432     */
#define OFF_CQKV  25970688ULL               /* 2304*4608*2  = 21,233,664 (bf16) */
#define OFF_ATTN  47204352ULL               /* 2304*1536*2  = 7,077,888  */
#define OFF_SC    54282240ULL               /* 32*256*128*4 = 4,194,304  */
/* total ~58.5 MB */

__device__ __forceinline__ u16 f2bf(float f) {
  __hip_bfloat16 h = __float2bfloat16(f);
  return *reinterpret_cast<u16*>(&h);
}
__device__ __forceinline__ float bf2f(u16 v) {
  uint32_t u = ((uint32_t)v) << 16;
  return __uint_as_float(u);
}

__device__ __forceinline__ void gload_lds16(const u16* g, u16* l) {
  __builtin_amdgcn_global_load_lds(
      (const __attribute__((address_space(1))) void*)g,
      (__attribute__((address_space(3))) void*)l,
      16, 0, 0);
}

/* ---- f32 -> bf16 cast, 8 elems/thread, zero-pad past n_src8 ---- */
__global__ void cast_pad8_kernel(const float* __restrict__ src, u16* __restrict__ dst,
                                 int n_src8, int n_tot8) {
  int i = blockIdx.x * 256 + threadIdx.x;
  if (i >= n_tot8) return;
  uint4 o;
  if (i < n_src8) {
    const float4 a = ((const float4*)src)[i * 2];
    const float4 b = ((const float4*)src)[i * 2 + 1];
    o.x = (uint32_t)f2bf(a.x) | ((uint32_t)f2bf(a.y) << 16);
    o.y = (uint32_t)f2bf(a.z) | ((uint32_t)f2bf(a.w) << 16);
    o.z = (uint32_t)f2bf(b.x) | ((uint32_t)f2bf(b.y) << 16);
    o.w = (uint32_t)f2bf(b.z) | ((uint32_t)f2bf(b.w) << 16);
  } else {
    o = make_uint4(0, 0, 0, 0);
  }
  ((uint4*)dst)[i] = o;
}

__global__ void pack_bias_kernel(const float* __restrict__ bq, const float* __restrict__ bk,
                                 const float* __restrict__ bv, float* __restrict__ dst) {
  int i = blockIdx.x * 256 + threadIdx.x;
  if (i >= NQKV) return;
  float v;
  if (i < DIM_)            v = bq[i];
  else if (i < 2 * DIM_)   v = bk[i - DIM_];
  else                     v = bv[i - 2 * DIM_];
  dst[i] = v;
}

/* ---- precompute sin/cos for cached-frame rope: sctab[f][z][j] = {sin,cos} ---- */
__global__ __launch_bounds__(256)
void sincos_kernel(const float* __restrict__ rope_table, const int* __restrict__ rope_idx,
                   float* __restrict__ sctab) {
  const int idx = blockIdx.x * 4 + (threadIdx.x >> 6);  /* f*ZS + z */
  const int j = threadIdx.x & 63;
  const int f = idx / ZS_, z = idx % ZS_;
  const int fi = rope_idx[f];
  const float fr = rope_table[((size_t)fi * L_ + z) * 64 + j];
  float sn, cn;
  __sincosf(fr, &sn, &cn);
  *(float2*)&sctab[((size_t)idx << 7) + 2 * j] = make_float2(sn, cn);
}

/* ---- bf16 GEMM, C[m,n] = sum_k A[m,k]*B[n,k] + bias[n]  (NT layout) ----
 * 128x128 tile, BK=32, 4 waves (2x2), global_load_lds w=16, 16x16x32 MFMA. */
__global__ __launch_bounds__(256)
void gemm_bt_kernel(const u16* __restrict__ A, const u16* __restrict__ Bm,
                    const float* __restrict__ bias, void* __restrict__ Cv,
                    int K, int ldc, int Mvalid, int bf16out) {
  const int tn = blockIdx.x, tm = blockIdx.y;
  const int tid = threadIdx.x;
  const int lane = tid & 63;
  const int wid = tid >> 6;
  const int wm = wid >> 1, wn = wid & 1;

  __shared__ __align__(16) u16 As[128 * 32];
  __shared__ __align__(16) u16 Bs[128 * 32];

  f32x4 acc[4][4] = {};

  const int srow = tid >> 2;
  const int scol = (tid & 3) * 8;
  const u16* Abase = A + (size_t)(tm * 128 + srow) * K + scol;
  const u16* Bbase = Bm + (size_t)(tn * 128 + srow) * K + scol;
  u16* lAs = &As[srow * 32 + scol];
  u16* lBs = &Bs[srow * 32 + scol];
  const size_t rstep = (size_t)64 * K;

  const int ko = (lane >> 4) * 8;
  const int rA = wm * 64 + (lane & 15);
  const int rB = wn * 64 + (lane & 15);

  for (int kt = 0; kt < K; kt += 32) {
    __syncthreads();
    gload_lds16(Abase + kt,         lAs);
    gload_lds16(Abase + kt + rstep, lAs + 64 * 32);
    gload_lds16(Bbase + kt,         lBs);
    gload_lds16(Bbase + kt + rstep, lBs + 64 * 32);
    __syncthreads();

    bf16x8 af[4], bfr[4];
#pragma unroll
    for (int f = 0; f < 4; ++f) {
      af[f]  = *(const bf16x8*)&As[(rA + f * 16) * 32 + ko];
      bfr[f] = *(const bf16x8*)&Bs[(rB + f * 16) * 32 + ko];
    }
#pragma unroll
    for (int fm = 0; fm < 4; ++fm)
#pragma unroll
      for (int fn = 0; fn < 4; ++fn)
        acc[fm][fn] = __builtin_amdgcn_mfma_f32_16x16x32_bf16(af[fm], bfr[fn], acc[fm][fn], 0, 0, 0);
  }

  const int m0 = tm * 128 + wm * 64 + (lane >> 4) * 4;
  const int n0 = tn * 128 + wn * 64 + (lane & 15);
#pragma unroll
  for (int fm = 0; fm < 4; ++fm) {
#pragma unroll
    for (int fn = 0; fn < 4; ++fn) {
      const int n = n0 + fn * 16;
      const float bv = bias[n];
#pragma unroll
      for (int r = 0; r < 4; ++r) {
        const int m = m0 + fm * 16 + r;
        if (m < Mvalid) {
          const float val = acc[fm][fn][r] + bv;
          if (bf16out) ((u16*)Cv)[(size_t)m * ldc + n] = f2bf(val);
          else         ((float*)Cv)[(size_t)m * ldc + n] = val;
        }
      }
    }
  }
}

/* ---- in-place RMSNorm on q,k (bf16 rows) + RoPE(q) at frame cf; z<ZS only ---- */
__global__ __launch_bounds__(256)
void rmsnorm_rope_kernel(u16* __restrict__ C, const float* __restrict__ g_q,
                         const float* __restrict__ g_k, const float* __restrict__ rope_table,
                         const int* __restrict__ cf_ptr) {
  const int z = blockIdx.x % ZS_;
  const int b = blockIdx.x / ZS_;
  const int m = b * L_ + z;
  const int tid = threadIdx.x;
  const int cf = *cf_ptr;
  u16* row = C + (size_t)m * NQKV;
  __shared__ float red[4];

  for (int sec = 0; sec < 2; ++sec) {
    u16* p = row + sec * DIM_;
    const float* gw = sec ? g_k : g_q;
    float vx[3], vy[3];
    float ss = 0.f;
#pragma unroll
    for (int j = 0; j < 3; ++j) {
      int pj = tid + j * 256;          /* pair index 0..767 */
      uint32_t u = *(const uint32_t*)&p[pj * 2];
      vx[j] = bf2f((u16)(u & 0xffff));
      vy[j] = bf2f((u16)(u >> 16));
      ss += vx[j] * vx[j] + vy[j] * vy[j];
    }
#pragma unroll
    for (int o = 32; o; o >>= 1) ss += __shfl_xor(ss, o);
    if ((tid & 63) == 0) red[tid >> 6] = ss;
    __syncthreads();
    const float tot = red[0] + red[1] + red[2] + red[3];
    const float r = rsqrtf(tot * (1.f / DIM_) + 1e-6f);
#pragma unroll
    for (int j = 0; j < 3; ++j) {
      int pj = tid + j * 256;
      float y0 = vx[j] * r * gw[pj * 2];
      float y1 = vy[j] * r * gw[pj * 2 + 1];
      if (sec == 0) {                  /* rope on q only */
        float fr = rope_table[((size_t)cf * L_ + z) * 64 + (pj & 63)];
        float sn, cn;
        __sincosf(fr, &sn, &cn);
        float o0 = y0 * cn - y1 * sn;
        float o1 = y0 * sn + y1 * cn;
        y0 = o0; y1 = o1;
      }
      *(uint32_t*)&p[pj * 2] = (uint32_t)f2bf(y0) | ((uint32_t)f2bf(y1) << 16);
    }
    __syncthreads();
  }
}

/* ---- attention: one wave per (b,z,head-pair); 16B/lane loads; online softmax ---- */
__global__ __launch_bounds__(256)
void attention_kernel(const u16* __restrict__ Cq, const float* __restrict__ cache_k,
                      const float* __restrict__ cache_v, const float* __restrict__ sctab,
                      const int* __restrict__ cf_ptr, u16* __restrict__ attn_in) {
  const int w = blockIdx.x * 4 + (threadIdx.x >> 6);
  const int lane = threadIdx.x & 63;
  const int hp = w % 6;
  const int z = (w / 6) % ZS_;
  const int b = w / (6 * ZS_);
  const int h = lane >> 5, il = lane & 31;
  const int n = hp * 2 + h;
  const int d0 = il * 4;
  const int cf = *cf_ptr;
  const int slot = cf % FH_;
  const int valid = min(cf + 1, FH_);

  const size_t crow = (size_t)(b * L_ + z) * NQKV + n * DH_ + d0;
  float q0, q1, q2, q3;
  {
    ushort4 qv = *(const ushort4*)&Cq[crow];
    q0 = bf2f(qv.x); q1 = bf2f(qv.y); q2 = bf2f(qv.z); q3 = bf2f(qv.w);
  }

  float mx = -1e30f, lsum = 0.f;
  float a0 = 0.f, a1 = 0.f, a2 = 0.f, a3 = 0.f;
  for (int g = 0; g < valid; ++g) {
    const float4 sc = *(const float4*)&sctab[((size_t)(g * ZS_ + z) << 7) + d0];
    float k0, k1, k2, k3, v0, v1, v2, v3;
    if (g == slot) {
      ushort4 kv = *(const ushort4*)&Cq[crow + DIM_];
      ushort4 vv = *(const ushort4*)&Cq[crow + 2 * DIM_];
      k0 = bf2f(kv.x); k1 = bf2f(kv.y); k2 = bf2f(kv.z); k3 = bf2f(kv.w);
      v0 = bf2f(vv.x); v1 = bf2f(vv.y); v2 = bf2f(vv.z); v3 = bf2f(vv.w);
    } else {
      const size_t coff = ((((size_t)b * FH_ + g) * L_ + z) * NH_ + n) * DH_ + d0;
      const float4 kk = *(const float4*)&cache_k[coff];
      const float4 vv = *(const float4*)&cache_v[coff];
      k0 = kk.x; k1 = kk.y; k2 = kk.z; k3 = kk.w;
      v0 = vv.x; v1 = vv.y; v2 = vv.z; v3 = vv.w;
    }
    /* rope(k): pairs (k0,k1) with (sin,cos)=(sc.x,sc.y); (k2,k3) with (sc.z,sc.w) */
    const float kr0 = k0 * sc.y - k1 * sc.x;
    const float kr1 = k0 * sc.x + k1 * sc.y;
    const float kr2 = k2 * sc.w - k3 * sc.z;
    const float kr3 = k2 * sc.z + k3 * sc.w;
    float part = q0 * kr0 + q1 * kr1 + q2 * kr2 + q3 * kr3;
#pragma unroll
    for (int o = 16; o; o >>= 1) part += __shfl_xor(part, o);
    const float score = part * 0.088388347648318447f; /* 1/sqrt(128) */
    const float nm = fmaxf(mx, score);
    const float scl = __expf(mx - nm);
    const float pw = __expf(score - nm);
    lsum = lsum * scl + pw;
    a0 = a0 * scl + pw * v0;
    a1 = a1 * scl + pw * v1;
    a2 = a2 * scl + pw * v2;
    a3 = a3 * scl + pw * v3;
    mx = nm;
  }
  const float inv = 1.f / lsum;
  uint2 o;
  o.x = (uint32_t)f2bf(a0 * inv) | ((uint32_t)f2bf(a1 * inv) << 16);
  o.y = (uint32_t)f2bf(a2 * inv) | ((uint32_t)f2bf(a3 * inv) << 16);
  *(uint2*)&attn_in[(size_t)(b * L_ + z) * DIM_ + n * DH_ + d0] = o;
}

/* ---- copy raw v rows (z >= ZS) into attn_in, 8 bf16/thread ---- */
__global__ void vcond_kernel(const u16* __restrict__ Cq, u16* __restrict__ attn_in) {
  int i = blockIdx.x * 256 + threadIdx.x;
  const int tot = B_ * (L_ - ZS_) * DIM_ / 8;   /* 26112 */
  if (i >= tot) return;
  int e = i * 8;
  int col = e % DIM_;
  int r = e / DIM_;
  int b = r / (L_ - ZS_);
  int lz = r % (L_ - ZS_);
  size_t mrow = (size_t)b * L_ + ZS_ + lz;
  *(uint4*)&attn_in[mrow * DIM_ + col] = *(const uint4*)&Cq[mrow * NQKV + 2 * DIM_ + col];
}

extern "C" void kernel_launch(void* const* d_in, const int* in_sizes, int n_in,
                              void* d_out, int out_size, void* d_ws, size_t ws_size,
                              hipStream_t stream) {
  const float* x       = (const float*)d_in[0];
  const float* w_q     = (const float*)d_in[1];
  const float* b_q     = (const float*)d_in[2];
  const float* w_k     = (const float*)d_in[3];
  const float* b_k     = (const float*)d_in[4];
  const float* w_v     = (const float*)d_in[5];
  const float* b_v     = (const float*)d_in[6];
  const float* w_o     = (const float*)d_in[7];
  const float* b_o     = (const float*)d_in[8];
  const float* g_q     = (const float*)d_in[9];
  const float* g_k     = (const float*)d_in[10];
  const float* cache_k = (const float*)d_in[11];
  const float* cache_v = (const float*)d_in[12];
  const float* rope_tb = (const float*)d_in[13];
  const int*   rope_ix = (const int*)d_in[14];
  const int*   cf      = (const int*)d_in[15];

  char* ws = (char*)d_ws;
  u16*   xb      = (u16*)(ws + OFF_XB);
  u16*   wb      = (u16*)(ws + OFF_WB);
  u16*   wob     = (u16*)(ws + OFF_WOB);
  float* bqkv    = (float*)(ws + OFF_BQKV);
  u16*   Cq      = (u16*)(ws + OFF_CQKV);
  u16*   attn_in = (u16*)(ws + OFF_ATTN);
  float* sctab   = (float*)(ws + OFF_SC);

  const int WN = DIM_ * DIM_;       /* 2,359,296 */
  const int WN8 = WN / 8;           /* 294,912   */
  const int X8 = MROWS * DIM_ / 8;  /* 419,328   */
  const int XT8 = MPAD * DIM_ / 8;  /* 442,368   */

  cast_pad8_kernel<<<(XT8 + 255) / 256, 256, 0, stream>>>(x, xb, X8, XT8);
  cast_pad8_kernel<<<(WN8 + 255) / 256, 256, 0, stream>>>(w_q, wb,          WN8, WN8);
  cast_pad8_kernel<<<(WN8 + 255) / 256, 256, 0, stream>>>(w_k, wb + WN,     WN8, WN8);
  cast_pad8_kernel<<<(WN8 + 255) / 256, 256, 0, stream>>>(w_v, wb + 2 * WN, WN8, WN8);
  cast_pad8_kernel<<<(WN8 + 255) / 256, 256, 0, stream>>>(w_o, wob,         WN8, WN8);
  pack_bias_kernel<<<(NQKV + 255) / 256, 256, 0, stream>>>(b_q, b_k, b_v, bqkv);
  sincos_kernel<<<FH_ * ZS_ / 4, 256, 0, stream>>>(rope_tb, rope_ix, sctab);

  /* QKV projection: (2304 x 4608 x 1536), bf16 out */
  gemm_bt_kernel<<<dim3(NQKV / 128, MPAD / 128), 256, 0, stream>>>(xb, wb, bqkv, Cq, DIM_, NQKV, MPAD, 1);

  /* RMSNorm(q,k) + RoPE(q), in place, z<ZS rows only */
  rmsnorm_rope_kernel<<<B_ * ZS_, 256, 0, stream>>>(Cq, g_q, g_k, rope_tb, cf);

  /* temporal attention over frames (z < ZS), head-pair waves */
  attention_kernel<<<(B_ * ZS_ * 6) / 4, 256, 0, stream>>>(Cq, cache_k, cache_v, sctab, cf, attn_in);

  /* passthrough v for z >= ZS */
  vcond_kernel<<<(B_ * (L_ - ZS_) * DIM_ / 8 + 255) / 256, 256, 0, stream>>>(Cq, attn_in);

  /* output projection: (2304 x 1536 x 1536), fp32 out, guarded at 2184 rows */
  gemm_bt_kernel<<<dim3(DIM_ / 128, MPAD / 128), 256, 0, stream>>>(attn_in, wob, b_o, (float*)d_out, DIM_, DIM_, MROWS, 0);
}

// Round 3
// 224.003 us; speedup vs baseline: 1.1638x; 1.1165x over previous
//
#include <hip/hip_runtime.h>
#include <hip/hip_bf16.h>
#include <stdint.h>

typedef unsigned short u16;
typedef __attribute__((ext_vector_type(8))) short bf16x8;
typedef __attribute__((ext_vector_type(4))) float f32x4;

#define B_    8
#define L_    273
#define DIM_  1536
#define NH_   12
#define DH_   128
#define ZS_   256
#define FH_   32
#define MROWS (B_ * L_)   /* 2184 */
#define MPAD  2304        /* 18 * 128 */
#define NQKV  4608
#define WN_   (DIM_ * DIM_)      /* 2,359,296 */
#define WN8_  (WN_ / 8)          /* 294,912   */
#define X8_   (MROWS * DIM_ / 8) /* 419,328   */
#define XT8_  (MPAD * DIM_ / 8)  /* 442,368   */

/* prep_kernel region boundaries (threads) */
#define N0_ 442368
#define N1_ 737280
#define N2_ 1032192
#define N3_ 1327104
#define N4_ 1622016
#define N5_ 1626624
#define N6_ 2150912
#define PREP_BLKS 8402

/* attention geometry */
#define ATTN_ITEMS (B_ * ZS_ * 6)     /* 12288 */
#define ATTN_BLKS  (ATTN_ITEMS / 2)   /* 6144  */
#define VCOND_TOT  (B_ * (L_ - ZS_) * DIM_ / 8)  /* 26112 */
#define VCOND_BLKS ((VCOND_TOT + 255) / 256)     /* 102   */

#define KSPLIT 768

/* workspace offsets (bytes), all 16B-aligned */
#define OFF_XB    0ULL                      /* 2304*1536*2  = 7,077,888  */
#define OFF_WB    7077888ULL                /* 4608*1536*2  = 14,155,776 */
#define OFF_WOB   21233664ULL               /* 1536*1536*2  = 4,718,592  */
#define OFF_BQKV  25952256ULL               /* 4608*4       = 18,432     */
#define OFF_CQKV  25970688ULL               /* 2304*4608*2  = 21,233,664 (bf16) */
#define OFF_ATTN  47204352ULL               /* 2304*1536*2  = 7,077,888  */
#define OFF_SC    54282240ULL               /* 32*256*128*4 = 4,194,304  */
/* split-K partials overlay dead regions:
 * p0 = [0, 14,155,776)        over xb + wb[0:7MB]  (dead after QKV GEMM)
 * p1 = [25,970,688, 40,126,464) over Cq            (dead after attention)  */
#define OFF_P0    0ULL
#define OFF_P1    25970688ULL

__device__ __forceinline__ u16 f2bf(float f) {
  __hip_bfloat16 h = __float2bfloat16(f);
  return *reinterpret_cast<u16*>(&h);
}
__device__ __forceinline__ float bf2f(u16 v) {
  uint32_t u = ((uint32_t)v) << 16;
  return __uint_as_float(u);
}

__device__ __forceinline__ void gload_lds16(const u16* g, u16* l) {
  __builtin_amdgcn_global_load_lds(
      (const __attribute__((address_space(1))) void*)g,
      (__attribute__((address_space(3))) void*)l,
      16, 0, 0);
}

__device__ __forceinline__ void cast8(const float* __restrict__ s, u16* __restrict__ d,
                                      int i, int nvalid) {
  uint4 o;
  if (i < nvalid) {
    const float4 a = ((const float4*)s)[i * 2];
    const float4 b = ((const float4*)s)[i * 2 + 1];
    o.x = (uint32_t)f2bf(a.x) | ((uint32_t)f2bf(a.y) << 16);
    o.y = (uint32_t)f2bf(a.z) | ((uint32_t)f2bf(a.w) << 16);
    o.z = (uint32_t)f2bf(b.x) | ((uint32_t)f2bf(b.y) << 16);
    o.w = (uint32_t)f2bf(b.z) | ((uint32_t)f2bf(b.w) << 16);
  } else {
    o = make_uint4(0, 0, 0, 0);
  }
  ((uint4*)d)[i] = o;
}

/* ---- all input prep in ONE launch: casts, bias pack, rope sincos table ---- */
__global__ __launch_bounds__(256)
void prep_kernel(const float* __restrict__ x, const float* __restrict__ w_q,
                 const float* __restrict__ w_k, const float* __restrict__ w_v,
                 const float* __restrict__ w_o, const float* __restrict__ bq,
                 const float* __restrict__ bk, const float* __restrict__ bv,
                 const float* __restrict__ rope_tb, const int* __restrict__ rope_ix,
                 u16* __restrict__ xb, u16* __restrict__ wb, u16* __restrict__ wob,
                 float* __restrict__ bqkv, float* __restrict__ sctab) {
  const int t = blockIdx.x * 256 + threadIdx.x;
  if (t < N0_)      cast8(x,   xb,           t,       X8_);
  else if (t < N1_) cast8(w_q, wb,           t - N0_, WN8_);
  else if (t < N2_) cast8(w_k, wb + WN_,     t - N1_, WN8_);
  else if (t < N3_) cast8(w_v, wb + 2 * WN_, t - N2_, WN8_);
  else if (t < N4_) cast8(w_o, wob,          t - N3_, WN8_);
  else if (t < N5_) {
    int i = t - N4_;
    float v;
    if (i < DIM_)          v = bq[i];
    else if (i < 2 * DIM_) v = bk[i - DIM_];
    else                   v = bv[i - 2 * DIM_];
    bqkv[i] = v;
  } else {
    int u = t - N5_;
    int j = u & 63;
    int idx = u >> 6;              /* f*ZS + z */
    int f = idx >> 8, z = idx & 255;
    int fi = rope_ix[f];
    float fr = rope_tb[((size_t)fi * L_ + z) * 64 + j];
    float sn, cn;
    __sincosf(fr, &sn, &cn);
    *(float2*)&sctab[((size_t)idx << 7) + 2 * j] = make_float2(sn, cn);
  }
}

/* ---- bf16 GEMM, C[m,n] = sum_k A[m,k]*B[n,k] (+bias)  (NT layout) ----
 * 128x128 tile, BK=32, 4 waves (2x2), double-buffered LDS with stage-early
 * (T3-minimum schedule: one barrier per K-step, loads in flight over MFMA).
 * mode 0: f32 out + bias; 1: bf16 out + bias; 2: f32 partial (split-K via
 * blockIdx.z, no bias, C0/C1 select). */
__global__ __launch_bounds__(256)
void gemm_bt_kernel(const u16* __restrict__ A, const u16* __restrict__ Bm,
                    const float* __restrict__ bias, void* __restrict__ Cv,
                    void* __restrict__ Cv2,
                    int K, int ldc, int Mvalid, int mode, int ksplit) {
  const int tn = blockIdx.x, tm = blockIdx.y;
  const int tid = threadIdx.x;
  const int lane = tid & 63;
  const int wid = tid >> 6;
  const int wm = wid >> 1, wn = wid & 1;

  __shared__ __align__(16) u16 As[2][128 * 32];
  __shared__ __align__(16) u16 Bs[2][128 * 32];

  f32x4 acc[4][4] = {};

  const int srow = tid >> 2;
  const int scol = (tid & 3) * 8;
  const u16* Abase = A + (size_t)(tm * 128 + srow) * K + scol;
  const u16* Bbase = Bm + (size_t)(tn * 128 + srow) * K + scol;
  const size_t rstep = (size_t)64 * K;
  const int lofs = srow * 32 + scol;

  const int ko = (lane >> 4) * 8;
  const int rA = wm * 64 + (lane & 15);
  const int rB = wn * 64 + (lane & 15);

  const int k0 = blockIdx.z * ksplit;
  const int k1 = k0 + ksplit;

  /* prologue: stage first K-step into buffer 0 */
  gload_lds16(Abase + k0,         &As[0][lofs]);
  gload_lds16(Abase + k0 + rstep, &As[0][64 * 32 + lofs]);
  gload_lds16(Bbase + k0,         &Bs[0][lofs]);
  gload_lds16(Bbase + k0 + rstep, &Bs[0][64 * 32 + lofs]);
  __syncthreads();

  int cur = 0;
  for (int kt = k0; kt < k1; kt += 32) {
    const int nx = cur ^ 1;
    if (kt + 32 < k1) {           /* issue next-tile loads BEFORE compute */
      gload_lds16(Abase + kt + 32,         &As[nx][lofs]);
      gload_lds16(Abase + kt + 32 + rstep, &As[nx][64 * 32 + lofs]);
      gload_lds16(Bbase + kt + 32,         &Bs[nx][lofs]);
      gload_lds16(Bbase + kt + 32 + rstep, &Bs[nx][64 * 32 + lofs]);
    }
    bf16x8 af[4], bfr[4];
#pragma unroll
    for (int f = 0; f < 4; ++f) {
      af[f]  = *(const bf16x8*)&As[cur][(rA + f * 16) * 32 + ko];
      bfr[f] = *(const bf16x8*)&Bs[cur][(rB + f * 16) * 32 + ko];
    }
#pragma unroll
    for (int fm = 0; fm < 4; ++fm)
#pragma unroll
      for (int fn = 0; fn < 4; ++fn)
        acc[fm][fn] = __builtin_amdgcn_mfma_f32_16x16x32_bf16(af[fm], bfr[fn], acc[fm][fn], 0, 0, 0);
    __syncthreads();              /* drains vmcnt (next tile landed) + lgkm */
    cur = nx;
  }

  const int m0 = tm * 128 + wm * 64 + (lane >> 4) * 4;
  const int n0 = tn * 128 + wn * 64 + (lane & 15);
  float* Cf = (mode == 2 && blockIdx.z) ? (float*)Cv2 : (float*)Cv;
#pragma unroll
  for (int fm = 0; fm < 4; ++fm) {
#pragma unroll
    for (int fn = 0; fn < 4; ++fn) {
      const int n = n0 + fn * 16;
      const float bv = (mode == 2) ? 0.f : bias[n];
#pragma unroll
      for (int r = 0; r < 4; ++r) {
        const int m = m0 + fm * 16 + r;
        if (m < Mvalid) {
          const float val = acc[fm][fn][r] + bv;
          if (mode == 1) ((u16*)Cv)[(size_t)m * ldc + n] = f2bf(val);
          else           Cf[(size_t)m * ldc + n] = val;
        }
      }
    }
  }
}

/* ---- in-place RMSNorm on q,k (bf16 rows) + RoPE(q) at frame cf; z<ZS only ---- */
__global__ __launch_bounds__(256)
void rmsnorm_rope_kernel(u16* __restrict__ C, const float* __restrict__ g_q,
                         const float* __restrict__ g_k, const float* __restrict__ rope_table,
                         const int* __restrict__ cf_ptr) {
  const int z = blockIdx.x % ZS_;
  const int b = blockIdx.x / ZS_;
  const int m = b * L_ + z;
  const int tid = threadIdx.x;
  const int cf = *cf_ptr;
  u16* row = C + (size_t)m * NQKV;
  __shared__ float red[4];

  for (int sec = 0; sec < 2; ++sec) {
    u16* p = row + sec * DIM_;
    const float* gw = sec ? g_k : g_q;
    float vx[3], vy[3];
    float ss = 0.f;
#pragma unroll
    for (int j = 0; j < 3; ++j) {
      int pj = tid + j * 256;          /* pair index 0..767 */
      uint32_t u = *(const uint32_t*)&p[pj * 2];
      vx[j] = bf2f((u16)(u & 0xffff));
      vy[j] = bf2f((u16)(u >> 16));
      ss += vx[j] * vx[j] + vy[j] * vy[j];
    }
#pragma unroll
    for (int o = 32; o; o >>= 1) ss += __shfl_xor(ss, o);
    if ((tid & 63) == 0) red[tid >> 6] = ss;
    __syncthreads();
    const float tot = red[0] + red[1] + red[2] + red[3];
    const float r = rsqrtf(tot * (1.f / DIM_) + 1e-6f);
#pragma unroll
    for (int j = 0; j < 3; ++j) {
      int pj = tid + j * 256;
      float y0 = vx[j] * r * gw[pj * 2];
      float y1 = vy[j] * r * gw[pj * 2 + 1];
      if (sec == 0) {                  /* rope on q only */
        float fr = rope_table[((size_t)cf * L_ + z) * 64 + (pj & 63)];
        float sn, cn;
        __sincosf(fr, &sn, &cn);
        float o0 = y0 * cn - y1 * sn;
        float o1 = y0 * sn + y1 * cn;
        y0 = o0; y1 = o1;
      }
      *(uint32_t*)&p[pj * 2] = (uint32_t)f2bf(y0) | ((uint32_t)f2bf(y1) << 16);
    }
    __syncthreads();
  }
}

/* ---- attention: 2 waves per (b,z,head-pair) split over g; LDS merge;
 *      vcond passthrough blocks appended at the end of the grid ---- */
__global__ __launch_bounds__(256)
void attention_kernel(const u16* __restrict__ Cq, const float* __restrict__ cache_k,
                      const float* __restrict__ cache_v, const float* __restrict__ sctab,
                      const int* __restrict__ cf_ptr, u16* __restrict__ attn_in) {
  if (blockIdx.x >= ATTN_BLKS) {
    /* v passthrough for rows z >= ZS, 8 bf16/thread */
    int i = (blockIdx.x - ATTN_BLKS) * 256 + threadIdx.x;
    if (i < VCOND_TOT) {
      int e = i * 8;
      int col = e % DIM_;
      int r = e / DIM_;
      int b = r / (L_ - ZS_);
      int lz = r % (L_ - ZS_);
      size_t mrow = (size_t)b * L_ + ZS_ + lz;
      *(uint4*)&attn_in[mrow * DIM_ + col] = *(const uint4*)&Cq[mrow * NQKV + 2 * DIM_ + col];
    }
    return;
  }

  __shared__ float sm[2][64][6];
  const int p = threadIdx.x >> 7;          /* item within block */
  const int wi = (threadIdx.x >> 6) & 1;   /* wave within item  */
  const int lane = threadIdx.x & 63;
  const int item = blockIdx.x * 2 + p;
  const int hp = item % 6;
  const int z = (item / 6) % ZS_;
  const int b = item / (6 * ZS_);
  const int h = lane >> 5, il = lane & 31;
  const int n = hp * 2 + h;
  const int d0 = il * 4;
  const int cf = *cf_ptr;
  const int slot = cf % FH_;
  const int valid = min(cf + 1, FH_);
  const int g0 = (valid + 1) >> 1;
  const int gs = wi ? g0 : 0;
  const int ge = wi ? valid : g0;

  const size_t crow = (size_t)(b * L_ + z) * NQKV + n * DH_ + d0;
  float q0, q1, q2, q3;
  {
    ushort4 qv = *(const ushort4*)&Cq[crow];
    q0 = bf2f(qv.x); q1 = bf2f(qv.y); q2 = bf2f(qv.z); q3 = bf2f(qv.w);
  }

  float mx = -1e30f, lsum = 0.f;
  float a0 = 0.f, a1 = 0.f, a2 = 0.f, a3 = 0.f;
  for (int g = gs; g < ge; ++g) {
    const float4 sc = *(const float4*)&sctab[((size_t)(g * ZS_ + z) << 7) + d0];
    float k0, k1, k2, k3, v0, v1, v2, v3;
    if (g == slot) {
      ushort4 kv = *(const ushort4*)&Cq[crow + DIM_];
      ushort4 vv = *(const ushort4*)&Cq[crow + 2 * DIM_];
      k0 = bf2f(kv.x); k1 = bf2f(kv.y); k2 = bf2f(kv.z); k3 = bf2f(kv.w);
      v0 = bf2f(vv.x); v1 = bf2f(vv.y); v2 = bf2f(vv.z); v3 = bf2f(vv.w);
    } else {
      const size_t coff = ((((size_t)b * FH_ + g) * L_ + z) * NH_ + n) * DH_ + d0;
      const float4 kk = *(const float4*)&cache_k[coff];
      const float4 vv = *(const float4*)&cache_v[coff];
      k0 = kk.x; k1 = kk.y; k2 = kk.z; k3 = kk.w;
      v0 = vv.x; v1 = vv.y; v2 = vv.z; v3 = vv.w;
    }
    const float kr0 = k0 * sc.y - k1 * sc.x;
    const float kr1 = k0 * sc.x + k1 * sc.y;
    const float kr2 = k2 * sc.w - k3 * sc.z;
    const float kr3 = k2 * sc.z + k3 * sc.w;
    float part = q0 * kr0 + q1 * kr1 + q2 * kr2 + q3 * kr3;
#pragma unroll
    for (int o = 16; o; o >>= 1) part += __shfl_xor(part, o);
    const float score = part * 0.088388347648318447f; /* 1/sqrt(128) */
    const float nm = fmaxf(mx, score);
    const float scl = __expf(mx - nm);
    const float pw = __expf(score - nm);
    lsum = lsum * scl + pw;
    a0 = a0 * scl + pw * v0;
    a1 = a1 * scl + pw * v1;
    a2 = a2 * scl + pw * v2;
    a3 = a3 * scl + pw * v3;
    mx = nm;
  }

  if (wi == 1) {
    sm[p][lane][0] = mx;  sm[p][lane][1] = lsum;
    sm[p][lane][2] = a0;  sm[p][lane][3] = a1;
    sm[p][lane][4] = a2;  sm[p][lane][5] = a3;
  }
  __syncthreads();
  if (wi == 0) {
    const float mB = sm[p][lane][0], lB = sm[p][lane][1];
    const float M = fmaxf(mx, mB);
    const float wA = __expf(mx - M), wB = __expf(mB - M);
    const float L = lsum * wA + lB * wB;
    const float inv = 1.f / L;
    const float o0 = (a0 * wA + sm[p][lane][2] * wB) * inv;
    const float o1 = (a1 * wA + sm[p][lane][3] * wB) * inv;
    const float o2 = (a2 * wA + sm[p][lane][4] * wB) * inv;
    const float o3 = (a3 * wA + sm[p][lane][5] * wB) * inv;
    uint2 o;
    o.x = (uint32_t)f2bf(o0) | ((uint32_t)f2bf(o1) << 16);
    o.y = (uint32_t)f2bf(o2) | ((uint32_t)f2bf(o3) << 16);
    *(uint2*)&attn_in[(size_t)(b * L_ + z) * DIM_ + n * DH_ + d0] = o;
  }
}

/* ---- split-K reduce + bias -> d_out (fp32), float4/thread ---- */
__global__ __launch_bounds__(256)
void reduce_kernel(const float* __restrict__ p0, const float* __restrict__ p1,
                   const float* __restrict__ b_o, float* __restrict__ out) {
  const int i = blockIdx.x * 256 + threadIdx.x;
  if (i >= MROWS * DIM_ / 4) return;
  const int col4 = i % (DIM_ / 4);
  const float4 a = ((const float4*)p0)[i];
  const float4 b = ((const float4*)p1)[i];
  const float4 c = ((const float4*)b_o)[col4];
  float4 o;
  o.x = a.x + b.x + c.x;
  o.y = a.y + b.y + c.y;
  o.z = a.z + b.z + c.z;
  o.w = a.w + b.w + c.w;
  ((float4*)out)[i] = o;
}

extern "C" void kernel_launch(void* const* d_in, const int* in_sizes, int n_in,
                              void* d_out, int out_size, void* d_ws, size_t ws_size,
                              hipStream_t stream) {
  const float* x       = (const float*)d_in[0];
  const float* w_q     = (const float*)d_in[1];
  const float* b_q     = (const float*)d_in[2];
  const float* w_k     = (const float*)d_in[3];
  const float* b_k     = (const float*)d_in[4];
  const float* w_v     = (const float*)d_in[5];
  const float* b_v     = (const float*)d_in[6];
  const float* w_o     = (const float*)d_in[7];
  const float* b_o     = (const float*)d_in[8];
  const float* g_q     = (const float*)d_in[9];
  const float* g_k     = (const float*)d_in[10];
  const float* cache_k = (const float*)d_in[11];
  const float* cache_v = (const float*)d_in[12];
  const float* rope_tb = (const float*)d_in[13];
  const int*   rope_ix = (const int*)d_in[14];
  const int*   cf      = (const int*)d_in[15];

  char* ws = (char*)d_ws;
  u16*   xb      = (u16*)(ws + OFF_XB);
  u16*   wb      = (u16*)(ws + OFF_WB);
  u16*   wob     = (u16*)(ws + OFF_WOB);
  float* bqkv    = (float*)(ws + OFF_BQKV);
  u16*   Cq      = (u16*)(ws + OFF_CQKV);
  u16*   attn_in = (u16*)(ws + OFF_ATTN);
  float* sctab   = (float*)(ws + OFF_SC);
  float* p0      = (float*)(ws + OFF_P0);
  float* p1      = (float*)(ws + OFF_P1);

  /* 1. all prep in one launch */
  prep_kernel<<<PREP_BLKS, 256, 0, stream>>>(x, w_q, w_k, w_v, w_o, b_q, b_k, b_v,
                                             rope_tb, rope_ix, xb, wb, wob, bqkv, sctab);

  /* 2. QKV projection (2304 x 4608 x 1536), bf16 out */
  gemm_bt_kernel<<<dim3(NQKV / 128, MPAD / 128, 1), 256, 0, stream>>>(
      xb, wb, bqkv, Cq, nullptr, DIM_, NQKV, MPAD, 1, DIM_);

  /* 3. RMSNorm(q,k) + RoPE(q), in place, z<ZS rows only */
  rmsnorm_rope_kernel<<<B_ * ZS_, 256, 0, stream>>>(Cq, g_q, g_k, rope_tb, cf);

  /* 4. temporal attention (split-g, 2 waves/item) + vcond passthrough */
  attention_kernel<<<ATTN_BLKS + VCOND_BLKS, 256, 0, stream>>>(
      Cq, cache_k, cache_v, sctab, cf, attn_in);

  /* 5. output projection (2304 x 1536 x 1536), split-K=2 partials */
  gemm_bt_kernel<<<dim3(DIM_ / 128, MPAD / 128, 2), 256, 0, stream>>>(
      attn_in, wob, nullptr, p0, p1, DIM_, DIM_, MPAD, 2, KSPLIT);

  /* 6. reduce partials + bias -> d_out */
  reduce_kernel<<<(MROWS * DIM_ / 4 + 255) / 256, 256, 0, stream>>>(p0, p1, b_o, (float*)d_out);
}